// Round 1
// baseline (41.461 us; speedup 1.0000x reference)
//
#include <hip/hip_runtime.h>

// Triplet hard loss: mean over (B+1)*B terms of relu(d_ap[i] - d_an + MARGIN)
// d_an enumerates ||a_i - b_j + eps|| for all j != i (the B-1 cyclic rolls),
// plus ||a_i - c_i + eps|| and ||a_i - d_i + eps||.
// B = 512, D = 256, fp32 throughout.

#define EPSV 1e-6f
#define MARGINV 1.0f

constexpr int BB = 512;   // batch
constexpr int DD = 256;   // feature dim
constexpr int D4 = DD / 4;
constexpr int TI = 8;     // i-rows per loss block
constexpr int TJ = 64;    // j-cols per loss block
constexpr int NBI = BB / TI;  // 64
constexpr int NBJ = BB / TJ;  // 8
constexpr float INV_N = 1.0f / (513.0f * 512.0f);

// ---------------------------------------------------------------------------
// Kernel A: diagonal distances. task = sel*512 + r:
//   sel 0 -> d_ap[r]  = ||a_r - b_r + eps||
//   sel 1 -> d_ac[r]  = ||a_r - c_r + eps||
//   sel 2 -> d_ad[r]  = ||a_r - d_r + eps||
// One wave (64 lanes) per task; lane covers 4 contiguous floats.
__global__ void __launch_bounds__(256) pdist_diag_kernel(
    const float* __restrict__ a, const float* __restrict__ b,
    const float* __restrict__ c, const float* __restrict__ d,
    float* __restrict__ ws_d) {
    int wid  = threadIdx.x >> 6;
    int lane = threadIdx.x & 63;
    int task = blockIdx.x * 4 + wid;          // 0..1535
    int sel  = task >> 9;
    int r    = task & (BB - 1);
    const float* x = (sel == 0) ? b : ((sel == 1) ? c : d);
    float4 av = reinterpret_cast<const float4*>(a)[r * D4 + lane];
    float4 xv = reinterpret_cast<const float4*>(x)[r * D4 + lane];
    float e0 = av.x - xv.x + EPSV;
    float e1 = av.y - xv.y + EPSV;
    float e2 = av.z - xv.z + EPSV;
    float e3 = av.w - xv.w + EPSV;
    float acc = e0 * e0 + e1 * e1 + e2 * e2 + e3 * e3;
    #pragma unroll
    for (int off = 32; off; off >>= 1) acc += __shfl_down(acc, off);
    if (lane == 0) ws_d[task] = sqrtf(acc);
}

// ---------------------------------------------------------------------------
// Kernel B: main loss. Block (bi,bj) handles i in [bi*8, bi*8+8) x
// j in [bj*64, bj*64+64). a-tile (+eps) staged in LDS; each thread computes
// 2 full distances and folds relu terms into a running sum.
__global__ void __launch_bounds__(256) triplet_loss_kernel(
    const float* __restrict__ a, const float* __restrict__ b,
    const float* __restrict__ ws_d, float* __restrict__ partial) {
    __shared__ float sA[TI * DD];   // a + eps
    __shared__ float sDap[TI];
    __shared__ float sRed[4];

    int t  = threadIdx.x;
    int bi = blockIdx.x >> 3;       // / NBJ
    int bj = blockIdx.x & (NBJ - 1);
    int i0 = bi * TI;
    int j0 = bj * TJ;

    // stage a' = a + eps : 2048 floats = 512 float4, 2 per thread (coalesced)
    {
        const float4* a4 = reinterpret_cast<const float4*>(a) + i0 * D4;
        float4* s4 = reinterpret_cast<float4*>(sA);
        #pragma unroll
        for (int r = 0; r < 2; ++r) {
            float4 v = a4[t + r * 256];
            v.x += EPSV; v.y += EPSV; v.z += EPSV; v.w += EPSV;
            s4[t + r * 256] = v;
        }
        if (t < TI) sDap[t] = ws_d[i0 + t];
    }
    __syncthreads();

    int il = t >> 5;                // 0..7
    int jl = t & 31;
    int ig = i0 + il;
    float dap = sDap[il];
    float s = 0.0f;

    #pragma unroll
    for (int ch = 0; ch < 2; ++ch) {
        int j = j0 + jl + 32 * ch;
        const float4* b4 = reinterpret_cast<const float4*>(b) + j * D4;
        const float4* s4 = reinterpret_cast<const float4*>(sA) + il * D4;
        float acc = 0.0f;
        #pragma unroll 8
        for (int d4 = 0; d4 < D4; ++d4) {
            float4 bv = b4[d4];
            float4 av = s4[d4];
            float e0 = av.x - bv.x;
            float e1 = av.y - bv.y;
            float e2 = av.z - bv.z;
            float e3 = av.w - bv.w;
            acc += e0 * e0 + e1 * e1 + e2 * e2 + e3 * e3;
        }
        if (j != ig) s += fmaxf(dap - sqrtf(acc) + MARGINV, 0.0f);
    }

    // c/d terms: once per i, added by the bj==0 blocks
    if (bj == 0 && jl < 2) {
        float dn = ws_d[BB + jl * BB + ig];   // jl=0 -> d_ac, jl=1 -> d_ad
        s += fmaxf(dap - dn + MARGINV, 0.0f);
    }

    // block reduction (deterministic)
    #pragma unroll
    for (int off = 32; off; off >>= 1) s += __shfl_down(s, off);
    if ((t & 63) == 0) sRed[t >> 6] = s;
    __syncthreads();
    if (t == 0) partial[blockIdx.x] = sRed[0] + sRed[1] + sRed[2] + sRed[3];
}

// ---------------------------------------------------------------------------
// Kernel C: deterministic sum of the 512 block partials -> mean
__global__ void __launch_bounds__(512) finalize_kernel(
    const float* __restrict__ partial, float* __restrict__ out) {
    __shared__ float sRed[8];
    int t = threadIdx.x;
    float s = partial[t];
    #pragma unroll
    for (int off = 32; off; off >>= 1) s += __shfl_down(s, off);
    if ((t & 63) == 0) sRed[t >> 6] = s;
    __syncthreads();
    if (t == 0) {
        float tot = 0.0f;
        #pragma unroll
        for (int w = 0; w < 8; ++w) tot += sRed[w];
        out[0] = tot * INV_N;
    }
}

extern "C" void kernel_launch(void* const* d_in, const int* in_sizes, int n_in,
                              void* d_out, int out_size, void* d_ws, size_t ws_size,
                              hipStream_t stream) {
    const float* a = (const float*)d_in[0];
    const float* b = (const float*)d_in[1];
    const float* c = (const float*)d_in[2];
    const float* d = (const float*)d_in[3];
    float* ws      = (float*)d_ws;
    float* dists   = ws;          // 1536 floats: dap | dac | dad
    float* partial = ws + 1536;   // 512 floats

    pdist_diag_kernel<<<384, 256, 0, stream>>>(a, b, c, d, dists);
    triplet_loss_kernel<<<NBI * NBJ, 256, 0, stream>>>(a, b, dists, partial);
    finalize_kernel<<<1, 512, 0, stream>>>(partial, (float*)d_out);
}

// Round 2
// 19.430 us; speedup vs baseline: 2.1339x; 2.1339x over previous
//
#include <hip/hip_runtime.h>
#include <hip/hip_bf16.h>

// TripletHardLoss, fully fused single kernel.
// loss = mean over i of: sum_{j != i} relu(d_ap[i] - ||a_i - b_j + eps|| + 1)
//                        + relu(d_ap[i] - ||a_i - c_i + eps|| + 1)
//                        + relu(d_ap[i] - ||a_i - d_i + eps|| + 1)
// mean over 513*512 terms.  With a' = a + eps:
//   ||a'_i - b_j||^2 = na[i] + nb[j] - 2 * (a'_i . b_j)
// The dot-product matrix is computed with bf16 MFMA (error ~2e-3 on the
// distance, threshold 2.3e-2); norms and diagonal distances in exact fp32.

#define EPSV 1e-6f
#define MARGINV 1.0f

typedef float  v4f  __attribute__((ext_vector_type(4)));
typedef short  s8v  __attribute__((ext_vector_type(8)));

constexpr int BB = 512;
constexpr int DD = 256;
constexpr int D4 = DD / 4;       // 64 float4 per row
constexpr int TT = 32;           // 32x32 output tile per block
constexpr int NB = BB / TT;      // 16
constexpr int NBLK = NB * NB;    // 256 blocks
constexpr float INV_N = 1.0f / (513.0f * 512.0f);

__device__ __forceinline__ unsigned short f2bf(float f) {
    unsigned int u = __float_as_uint(f);
    unsigned int r = (u + 0x7FFFu + ((u >> 16) & 1u)) >> 16;   // RNE
    return (unsigned short)r;
}

__global__ void __launch_bounds__(256) triplet_fused_kernel(
    const float* __restrict__ a, const float* __restrict__ b,
    const float* __restrict__ c, const float* __restrict__ d,
    float* __restrict__ partial, unsigned int* __restrict__ cnt,
    float* __restrict__ out)
{
    __shared__ __align__(16) unsigned short sA[TT * DD];  // bf16 a' tile, swizzled
    __shared__ __align__(16) unsigned short sB[TT * DD];  // bf16 b  tile, swizzled
    __shared__ float sNa[TT], sNb[TT], sDap[TT], sDac[TT], sDad[TT];
    __shared__ float sRed[4];
    __shared__ int   sLast;

    const int t  = threadIdx.x;
    const int bi = blockIdx.x >> 4;       // / NB
    const int bj = blockIdx.x & (NB - 1);
    const int i0 = bi * TT;
    const int j0 = bj * TT;

    // ---- stage a' and b tiles -> bf16 LDS (XOR-swizzled 16B slots) --------
    // 32 rows x 64 float4 = 2048 float4 per tile; 8 per thread, coalesced.
    {
        const float4* a4 = (const float4*)a;
        const float4* b4 = (const float4*)b;
        #pragma unroll
        for (int kk = 0; kk < 8; ++kk) {
            int idx  = t + kk * 256;
            int row  = idx >> 6;          // 0..31
            int col4 = idx & 63;          // float4 column
            int sw   = (row & 7) << 3;    // ushort-index XOR = byte XOR <<4

            float4 av = a4[(i0 + row) * D4 + col4];
            av.x += EPSV; av.y += EPSV; av.z += EPSV; av.w += EPSV;
            unsigned int lo = f2bf(av.x) | ((unsigned int)f2bf(av.y) << 16);
            unsigned int hi = f2bf(av.z) | ((unsigned int)f2bf(av.w) << 16);
            *(uint2*)&sA[(row * DD + col4 * 4) ^ sw] = make_uint2(lo, hi);

            float4 bv = b4[(j0 + row) * D4 + col4];
            lo = f2bf(bv.x) | ((unsigned int)f2bf(bv.y) << 16);
            hi = f2bf(bv.z) | ((unsigned int)f2bf(bv.w) << 16);
            *(uint2*)&sB[(row * DD + col4 * 4) ^ sw] = make_uint2(lo, hi);
        }
    }

    // ---- phase 1: fp32 row norms + diagonal distances ----------------------
    // row = t>>3 (0..31), seg = t&7; each thread covers 8 float4 of the row.
    {
        const int row = t >> 3, seg = t & 7;
        const float4* a4 = (const float4*)a;
        const float4* b4 = (const float4*)b;
        float na = 0.f, nb = 0.f, dap = 0.f;
        #pragma unroll
        for (int q = 0; q < 8; ++q) {
            int c4 = seg + q * 8;
            float4 av = a4[(i0 + row) * D4 + c4];
            av.x += EPSV; av.y += EPSV; av.z += EPSV; av.w += EPSV;
            float4 bjv = b4[(j0 + row) * D4 + c4];
            float4 biv = b4[(i0 + row) * D4 + c4];
            na += av.x * av.x + av.y * av.y + av.z * av.z + av.w * av.w;
            nb += bjv.x * bjv.x + bjv.y * bjv.y + bjv.z * bjv.z + bjv.w * bjv.w;
            float e0 = av.x - biv.x, e1 = av.y - biv.y;
            float e2 = av.z - biv.z, e3 = av.w - biv.w;
            dap += e0 * e0 + e1 * e1 + e2 * e2 + e3 * e3;
        }
        #pragma unroll
        for (int off = 4; off; off >>= 1) {
            na  += __shfl_down(na,  off, 8);
            nb  += __shfl_down(nb,  off, 8);
            dap += __shfl_down(dap, off, 8);
        }
        if (seg == 0) { sNa[row] = na; sNb[row] = nb; sDap[row] = sqrtf(dap); }

        if (bj == 0) {   // this block also owns the c/d terms for its 32 rows
            const float4* c4p = (const float4*)c;
            const float4* d4p = (const float4*)d;
            float dac = 0.f, dad = 0.f;
            #pragma unroll
            for (int q = 0; q < 8; ++q) {
                int c4 = seg + q * 8;
                float4 av = a4[(i0 + row) * D4 + c4];
                av.x += EPSV; av.y += EPSV; av.z += EPSV; av.w += EPSV;
                float4 cv = c4p[(i0 + row) * D4 + c4];
                float4 dv = d4p[(i0 + row) * D4 + c4];
                float e0 = av.x - cv.x, e1 = av.y - cv.y;
                float e2 = av.z - cv.z, e3 = av.w - cv.w;
                dac += e0 * e0 + e1 * e1 + e2 * e2 + e3 * e3;
                e0 = av.x - dv.x; e1 = av.y - dv.y;
                e2 = av.z - dv.z; e3 = av.w - dv.w;
                dad += e0 * e0 + e1 * e1 + e2 * e2 + e3 * e3;
            }
            #pragma unroll
            for (int off = 4; off; off >>= 1) {
                dac += __shfl_down(dac, off, 8);
                dad += __shfl_down(dad, off, 8);
            }
            if (seg == 0) { sDac[row] = sqrtf(dac); sDad[row] = sqrtf(dad); }
        }
    }
    __syncthreads();

    // ---- MFMA: G = A' * B^T for the 32x32 tile -----------------------------
    // wave w -> 16x16 sub-tile (wi = w>>1, wj = w&1).
    // A-frag: lane holds A[row = l&15][k = 32*kc + (l>>4)*8 + 0..7]  (b128)
    // B-frag: lane holds B[col = l&15][same k]                        (b128)
    const int l  = t & 63, w = t >> 6;
    const int wi = w >> 1, wj = w & 1;
    const int arow = wi * 16 + (l & 15);
    const int brow = wj * 16 + (l & 15);
    const int asw = (arow & 7) << 3;
    const int bsw = (brow & 7) << 3;
    const int kbase = (l >> 4) * 8;

    v4f acc = {0.f, 0.f, 0.f, 0.f};
    #pragma unroll
    for (int kc = 0; kc < 8; ++kc) {
        int k0 = kc * 32 + kbase;
        s8v af = *(const s8v*)&sA[(arow * DD + k0) ^ asw];
        s8v bf = *(const s8v*)&sB[(brow * DD + k0) ^ bsw];
        acc = __builtin_amdgcn_mfma_f32_16x16x32_bf16(af, bf, acc, 0, 0, 0);
    }

    // ---- epilogue: distances + relu terms ----------------------------------
    // C/D layout: col = lane&15, row = (lane>>4)*4 + reg   [m89 verified]
    float s = 0.f;
    const int jl = wj * 16 + (l & 15);
    const int jg = j0 + jl;
    const float nbj = sNb[jl];
    #pragma unroll
    for (int r = 0; r < 4; ++r) {
        int il = wi * 16 + (l >> 4) * 4 + r;
        int ig = i0 + il;
        float D2 = sNa[il] + nbj - 2.0f * acc[r];
        float dist = sqrtf(fmaxf(D2, 0.f));
        if (ig != jg) s += fmaxf(sDap[il] - dist + MARGINV, 0.f);
    }
    if (bj == 0 && t < TT) {
        s += fmaxf(sDap[t] - sDac[t] + MARGINV, 0.f);
        s += fmaxf(sDap[t] - sDad[t] + MARGINV, 0.f);
    }

    // ---- deterministic block reduction -------------------------------------
    #pragma unroll
    for (int off = 32; off; off >>= 1) s += __shfl_down(s, off);
    if (l == 0) sRed[w] = s;
    __syncthreads();

    if (t == 0) {
        partial[blockIdx.x] = sRed[0] + sRed[1] + sRed[2] + sRed[3];
        __threadfence();                       // release partial
        unsigned int old = atomicAdd(cnt, 1u); // device-scope
        sLast = (old == NBLK - 1) ? 1 : 0;
    }
    __syncthreads();

    // ---- last block: deterministic fixed-order final sum -------------------
    if (sLast && t < 64) {
        __threadfence();                       // acquire others' partials
        float x0 = partial[t];
        float x1 = partial[t + 64];
        float x2 = partial[t + 128];
        float x3 = partial[t + 192];
        float x = ((x0 + x1) + x2) + x3;
        #pragma unroll
        for (int off = 32; off; off >>= 1) x += __shfl_down(x, off);
        if (t == 0) out[0] = x * INV_N;
    }
}

extern "C" void kernel_launch(void* const* d_in, const int* in_sizes, int n_in,
                              void* d_out, int out_size, void* d_ws, size_t ws_size,
                              hipStream_t stream) {
    const float* a = (const float*)d_in[0];
    const float* b = (const float*)d_in[1];
    const float* c = (const float*)d_in[2];
    const float* d = (const float*)d_in[3];
    float* ws      = (float*)d_ws;
    float* partial = ws;                         // 256 floats
    unsigned int* cnt = (unsigned int*)(ws + 256);

    hipMemsetAsync(cnt, 0, sizeof(unsigned int), stream);
    triplet_fused_kernel<<<NBLK, 256, 0, stream>>>(a, b, c, d, partial, cnt,
                                                   (float*)d_out);
}

// Round 3
// 11.550 us; speedup vs baseline: 3.5896x; 1.6821x over previous
//
#include <hip/hip_runtime.h>
#include <hip/hip_bf16.h>

// TripletHardLoss: loss = mean over 513*512 terms of
//   relu(d_ap[i] - d_an + 1), d_an over all ||a_i - b_j + eps|| (j != i),
//   plus ||a_i - c_i + eps|| and ||a_i - d_i + eps||.
// With a' = a + eps:  ||a'_i - b_j||^2 = na[i] + nb[j] - 2 (a'_i . b_j).
// Gram matrix via bf16 MFMA (per-distance err ~2e-3, washes out in the mean);
// norms + diagonal distances in exact fp32.
// Two plain kernels, no atomics/fences: tile partials -> 1-wave reduce.

#define EPSV 1e-6f
#define MARGINV 1.0f

typedef float  v4f  __attribute__((ext_vector_type(4)));
typedef short  s8v  __attribute__((ext_vector_type(8)));

constexpr int BB = 512;
constexpr int DD = 256;
constexpr int D4 = DD / 4;       // 64 float4 per row
constexpr int TT = 32;           // 32x32 output tile per block
constexpr int NB = BB / TT;      // 16
constexpr int NBLK = NB * NB;    // 256 blocks
constexpr float INV_N = 1.0f / (513.0f * 512.0f);

__device__ __forceinline__ unsigned short f2bf(float f) {
    unsigned int u = __float_as_uint(f);
    unsigned int r = (u + 0x7FFFu + ((u >> 16) & 1u)) >> 16;   // RNE
    return (unsigned short)r;
}

__global__ void __launch_bounds__(256) triplet_tile_kernel(
    const float* __restrict__ a, const float* __restrict__ b,
    const float* __restrict__ c, const float* __restrict__ d,
    float* __restrict__ partial)
{
    __shared__ __align__(16) unsigned short sA[TT * DD];  // bf16 a' tile, swizzled
    __shared__ __align__(16) unsigned short sB[TT * DD];  // bf16 b  tile, swizzled
    __shared__ float sNa[TT], sNb[TT], sDap[TT], sDac[TT], sDad[TT];
    __shared__ float sRed[4];

    const int t  = threadIdx.x;
    const int bi = blockIdx.x >> 4;       // / NB
    const int bj = blockIdx.x & (NB - 1);
    const int i0 = bi * TT;
    const int j0 = bj * TT;

    // ---- stage a' and b tiles -> bf16 LDS (XOR-swizzled 16B slots) --------
    // 32 rows x 64 float4 per tile; 8 float4 per thread, wave = 1 KB contig.
    {
        const float4* a4 = (const float4*)a;
        const float4* b4 = (const float4*)b;
        #pragma unroll
        for (int kk = 0; kk < 8; ++kk) {
            int idx  = t + kk * 256;
            int row  = idx >> 6;          // 0..31
            int col4 = idx & 63;          // float4 column
            int sw   = (row & 7) << 3;    // ushort-index XOR = byte XOR <<4

            float4 av = a4[(i0 + row) * D4 + col4];
            av.x += EPSV; av.y += EPSV; av.z += EPSV; av.w += EPSV;
            unsigned int lo = f2bf(av.x) | ((unsigned int)f2bf(av.y) << 16);
            unsigned int hi = f2bf(av.z) | ((unsigned int)f2bf(av.w) << 16);
            *(uint2*)&sA[(row * DD + col4 * 4) ^ sw] = make_uint2(lo, hi);

            float4 bv = b4[(j0 + row) * D4 + col4];
            lo = f2bf(bv.x) | ((unsigned int)f2bf(bv.y) << 16);
            hi = f2bf(bv.z) | ((unsigned int)f2bf(bv.w) << 16);
            *(uint2*)&sB[(row * DD + col4 * 4) ^ sw] = make_uint2(lo, hi);
        }
    }

    // ---- phase 1: fp32 row norms + diagonal distances ----------------------
    // row = t>>3 (0..31), seg = t&7; 8 lanes cover one row (128B chunks).
    {
        const int row = t >> 3, seg = t & 7;
        const float4* a4 = (const float4*)a;
        const float4* b4 = (const float4*)b;
        float na = 0.f, nb = 0.f, dap = 0.f;
        #pragma unroll
        for (int q = 0; q < 8; ++q) {
            int c4 = seg + q * 8;
            float4 av = a4[(i0 + row) * D4 + c4];
            av.x += EPSV; av.y += EPSV; av.z += EPSV; av.w += EPSV;
            float4 bjv = b4[(j0 + row) * D4 + c4];
            float4 biv = b4[(i0 + row) * D4 + c4];
            na += av.x * av.x + av.y * av.y + av.z * av.z + av.w * av.w;
            nb += bjv.x * bjv.x + bjv.y * bjv.y + bjv.z * bjv.z + bjv.w * bjv.w;
            float e0 = av.x - biv.x, e1 = av.y - biv.y;
            float e2 = av.z - biv.z, e3 = av.w - biv.w;
            dap += e0 * e0 + e1 * e1 + e2 * e2 + e3 * e3;
        }
        #pragma unroll
        for (int off = 4; off; off >>= 1) {
            na  += __shfl_down(na,  off, 8);
            nb  += __shfl_down(nb,  off, 8);
            dap += __shfl_down(dap, off, 8);
        }
        if (seg == 0) { sNa[row] = na; sNb[row] = nb; sDap[row] = sqrtf(dap); }

        if (bj == 0) {   // bj==0 blocks own the c/d terms for their 32 rows
            const float4* c4p = (const float4*)c;
            const float4* d4p = (const float4*)d;
            float dac = 0.f, dad = 0.f;
            #pragma unroll
            for (int q = 0; q < 8; ++q) {
                int c4 = seg + q * 8;
                float4 av = a4[(i0 + row) * D4 + c4];
                av.x += EPSV; av.y += EPSV; av.z += EPSV; av.w += EPSV;
                float4 cv = c4p[(i0 + row) * D4 + c4];
                float4 dv = d4p[(i0 + row) * D4 + c4];
                float e0 = av.x - cv.x, e1 = av.y - cv.y;
                float e2 = av.z - cv.z, e3 = av.w - cv.w;
                dac += e0 * e0 + e1 * e1 + e2 * e2 + e3 * e3;
                e0 = av.x - dv.x; e1 = av.y - dv.y;
                e2 = av.z - dv.z; e3 = av.w - dv.w;
                dad += e0 * e0 + e1 * e1 + e2 * e2 + e3 * e3;
            }
            #pragma unroll
            for (int off = 4; off; off >>= 1) {
                dac += __shfl_down(dac, off, 8);
                dad += __shfl_down(dad, off, 8);
            }
            if (seg == 0) { sDac[row] = sqrtf(dac); sDad[row] = sqrtf(dad); }
        }
    }
    __syncthreads();

    // ---- MFMA: G = A' * B^T for the 32x32 tile -----------------------------
    // wave w -> 16x16 sub-tile (wi = w>>1, wj = w&1).
    const int l  = t & 63, w = t >> 6;
    const int wi = w >> 1, wj = w & 1;
    const int arow = wi * 16 + (l & 15);
    const int brow = wj * 16 + (l & 15);
    const int asw = (arow & 7) << 3;
    const int bsw = (brow & 7) << 3;
    const int kbase = (l >> 4) * 8;

    v4f acc = {0.f, 0.f, 0.f, 0.f};
    #pragma unroll
    for (int kc = 0; kc < 8; ++kc) {
        int k0 = kc * 32 + kbase;
        s8v af = *(const s8v*)&sA[(arow * DD + k0) ^ asw];
        s8v bf = *(const s8v*)&sB[(brow * DD + k0) ^ bsw];
        acc = __builtin_amdgcn_mfma_f32_16x16x32_bf16(af, bf, acc, 0, 0, 0);
    }

    // ---- epilogue: distances + relu terms ----------------------------------
    // C/D layout: col = lane&15, row = (lane>>4)*4 + reg   [m89 verified]
    float s = 0.f;
    const int jl = wj * 16 + (l & 15);
    const int jg = j0 + jl;
    const float nbj = sNb[jl];
    #pragma unroll
    for (int r = 0; r < 4; ++r) {
        int il = wi * 16 + (l >> 4) * 4 + r;
        int ig = i0 + il;
        float D2 = sNa[il] + nbj - 2.0f * acc[r];
        float dist = sqrtf(fmaxf(D2, 0.f));
        if (ig != jg) s += fmaxf(sDap[il] - dist + MARGINV, 0.f);
    }
    if (bj == 0 && t < TT) {
        s += fmaxf(sDap[t] - sDac[t] + MARGINV, 0.f);
        s += fmaxf(sDap[t] - sDad[t] + MARGINV, 0.f);
    }

    // ---- deterministic block reduction -> one partial per block ------------
    #pragma unroll
    for (int off = 32; off; off >>= 1) s += __shfl_down(s, off);
    if (l == 0) sRed[w] = s;
    __syncthreads();
    if (t == 0) partial[blockIdx.x] = sRed[0] + sRed[1] + sRed[2] + sRed[3];
}

// ---------------------------------------------------------------------------
// Final deterministic fixed-order sum of the 256 partials.
__global__ void __launch_bounds__(64) triplet_reduce_kernel(
    const float* __restrict__ partial, float* __restrict__ out)
{
    int t = threadIdx.x;
    float x0 = partial[t];
    float x1 = partial[t + 64];
    float x2 = partial[t + 128];
    float x3 = partial[t + 192];
    float x = ((x0 + x1) + x2) + x3;
    #pragma unroll
    for (int off = 32; off; off >>= 1) x += __shfl_down(x, off);
    if (t == 0) out[0] = x * INV_N;
}

extern "C" void kernel_launch(void* const* d_in, const int* in_sizes, int n_in,
                              void* d_out, int out_size, void* d_ws, size_t ws_size,
                              hipStream_t stream) {
    const float* a = (const float*)d_in[0];
    const float* b = (const float*)d_in[1];
    const float* c = (const float*)d_in[2];
    const float* d = (const float*)d_in[3];
    float* partial = (float*)d_ws;               // 256 floats

    triplet_tile_kernel<<<NBLK, 256, 0, stream>>>(a, b, c, d, partial);
    triplet_reduce_kernel<<<1, 64, 0, stream>>>(partial, (float*)d_out);
}